// Round 9
// baseline (389.368 us; speedup 1.0000x reference)
//
#include <hip/hip_runtime.h>

// SwappedPredictionLoss: Sinkhorn-Knopp (3 iters) + swapped cross-entropy.
//
// q[b,k] = B * e_bk * u_b * v_k,  e = exp(S/eps)
//   row-normalize: v_k = 1/(K*R_k),  R_k = sum_b e_bk * u_b
//   col-normalize: u_b = 1/(B*C_b),  C_b = sum_k e_bk * v_k
// loss = sum_pairs [ (1/B) sum_b lse_t[b] - sum_b u_b * sum_k e_s*v_k*(S_t/T) ]
// From e alone (eps/T = 0.5):  S/T = 0.5*ln(e),  exp(S/T) = sqrt(e).
//
// R4: naive fusion latency-bound. R5: hot global atomics serialize — banned.
// R6: privatized partial planes. R7: fp8 e4m3 E, 228us; ~half is kernel-
// boundary overhead (10 dispatches). R8: hipLaunchCooperativeKernel silently
// fails on this harness (output stayed 0) + 2 row-coverage bugs.
// R9: ONE REGULAR launch, manual hierarchical grid barrier in ws.
//   512 blocks, launch_bounds(256,2) => >=2 blocks/CU capacity => all 512
//   co-resident => spin barrier deadlock-free. __threadfence() = agent scope
//   (L2 wb/inv) handles cross-XCD visibility. Per-barrier dedicated counters.
// Harness note: integer inputs arrive as int32 (not int64).

#define NVIEWS 2
#define BATCH 4096
#define KPROTO 3000
#define KB 3072      // padded fp8 row stride (bytes); V row length (floats)
#define NT 256
#define CS 16        // rows per chunk
#define NCHUNK 256   // BATCH / CS
#define NBLK 512     // 2 views * 256 chunks
#define NBAR 7
// barrier area (uints): cnt[7][8][16] | root[7][16] | flag[7][8][16]
#define BAR_CNT(bid, g) ((bid) * 8 * 16 + (g) * 16)
#define BAR_ROOT(bid) (7 * 8 * 16 + (bid) * 16)
#define BAR_FLAG(bid, g) (7 * 8 * 16 + 7 * 16 + (bid) * 8 * 16 + (g) * 16)
#define BAR_UINTS (7 * 8 * 16 + 7 * 16 + 7 * 8 * 16)  // 1904

constexpr float EPS_INV = 20.0f;  // 1/0.05
constexpr float KF = 3000.0f;
constexpr float BF = 4096.0f;

typedef float floatx2 __attribute__((ext_vector_type(2)));

__device__ __forceinline__ float fast_rcp(float x) { return __builtin_amdgcn_rcpf(x); }
__device__ __forceinline__ float fast_sqrt(float x) { return __builtin_amdgcn_sqrtf(x); }

__device__ __forceinline__ float wave_sum(float x) {
#pragma unroll
  for (int o = 32; o > 0; o >>= 1) x += __shfl_down(x, o, 64);
  return x;
}

__device__ __forceinline__ float4 dec4(unsigned u) {
  floatx2 lo = __builtin_amdgcn_cvt_pk_f32_fp8((int)u, false);
  floatx2 hi = __builtin_amdgcn_cvt_pk_f32_fp8((int)u, true);
  return make_float4(lo.x, lo.y, hi.x, hi.y);
}

// Hierarchical grid barrier: 8 groups of 64 blocks -> root -> 8 release flags.
__device__ __forceinline__ void grid_barrier(unsigned* bar, int bid, int blk) {
  __syncthreads();
  if (threadIdx.x == 0) {
    __threadfence();  // release: flush my writes to device scope (L2 wb)
    const int g = blk & 7;
    if (atomicAdd(bar + BAR_CNT(bid, g), 1u) == 63u) {   // last of my group
      if (atomicAdd(bar + BAR_ROOT(bid), 1u) == 7u) {    // last group overall
        __threadfence();
#pragma unroll
        for (int i = 0; i < 8; ++i) atomicExch(bar + BAR_FLAG(bid, i), 1u);
      }
    }
    while (atomicAdd(bar + BAR_FLAG(bid, g), 0u) == 0u) __builtin_amdgcn_s_sleep(16);
    __threadfence();  // acquire: invalidate stale cached data
  }
  __syncthreads();
}

// V[v][k] = 1/max(K * sum_y P[v][y][k], tiny). Blocks 0..11 only.
__device__ __forceinline__ void reduce_phase(const float* __restrict__ P,
                                             float* __restrict__ V, int blk, int tid) {
  if (blk < 12) {
    const int v = blk / 6;
    const int sub = blk - v * 6;
    const int f2 = sub * NT + tid;  // float2 col index, 0..1535
    const float2* base = (const float2*)(P + (size_t)v * NCHUNK * KB) + f2;
    float2 a = make_float2(0.f, 0.f);
#pragma unroll 8
    for (int y = 0; y < NCHUNK; ++y) {
      float2 p = base[(size_t)y * (KB / 2)];
      a.x += p.x;
      a.y += p.y;
    }
    float2 o;
    o.x = fast_rcp(fmaxf(a.x * KF, 1e-35f));
    o.y = fast_rcp(fmaxf(a.y * KF, 1e-35f));
    ((float2*)(V + v * KB))[f2] = o;
  }
}

// Fused col-normalize + next row-partials for one 16-row chunk:
// phase A: 4 waves x 4 rows rowsum -> u in LDS; phase B: colsum(u) -> P plane.
__device__ __forceinline__ void fused_phase(const unsigned char* __restrict__ E,
                                            const float* __restrict__ V,
                                            float* __restrict__ P, int v, int c,
                                            int wv, int ln, int tid, float* u_s) {
  const float4* V4 = (const float4*)(V + v * KB);
#pragma unroll
  for (int r = 0; r < 4; ++r) {
    const int bl = wv * 4 + r;  // 0..15
    const uint4* Erow = (const uint4*)(E + ((size_t)v * BATCH + c * CS + bl) * KB);
    float acc = 0.f;
#pragma unroll
    for (int q = 0; q < 3; ++q) {
      const int f = q * 64 + ln;  // 16-fp8 group
      uint4 pk = Erow[f];
      float4 e0 = dec4(pk.x), e1 = dec4(pk.y), e2 = dec4(pk.z), e3 = dec4(pk.w);
      float4 v0 = V4[4 * f], v1 = V4[4 * f + 1], v2 = V4[4 * f + 2], v3 = V4[4 * f + 3];
      acc += e0.x * v0.x + e0.y * v0.y + e0.z * v0.z + e0.w * v0.w
           + e1.x * v1.x + e1.y * v1.y + e1.z * v1.z + e1.w * v1.w
           + e2.x * v2.x + e2.y * v2.y + e2.z * v2.z + e2.w * v2.w
           + e3.x * v3.x + e3.y * v3.y + e3.z * v3.z + e3.w * v3.w;
    }
    acc = wave_sum(acc);
    if (ln == 0) u_s[bl] = fast_rcp(acc * BF);
  }
  __syncthreads();
  const unsigned* Ecol = (const unsigned*)(E + ((size_t)v * BATCH + c * CS) * KB);
  float* Pp = P + (size_t)(v * NCHUNK + c) * KB;
#pragma unroll
  for (int sub = 0; sub < 3; ++sub) {
    const int f = sub * NT + tid;  // 4-col group, 0..767
    float4 acc = make_float4(0.f, 0.f, 0.f, 0.f);
#pragma unroll 4
    for (int b = 0; b < CS; ++b) {
      float u = u_s[b];
      float4 e = dec4(Ecol[(size_t)b * (KB / 4) + f]);
      acc.x += e.x * u; acc.y += e.y * u; acc.z += e.z * u; acc.w += e.w * u;
    }
    ((float4*)Pp)[f] = acc;
  }
  __syncthreads();
}

__global__ __launch_bounds__(NT, 2) void mega_kernel(
    const float* __restrict__ S, const int* __restrict__ ci,
    const int* __restrict__ si, unsigned char* __restrict__ E,
    float* __restrict__ P, float* __restrict__ V,
    float* __restrict__ partials, unsigned* __restrict__ bar,
    float* __restrict__ out) {
  const int blk = blockIdx.x;
  const int tid = threadIdx.x;
  const int v = blk >> 8;
  const int c = blk & 255;
  const int wv = tid >> 6, ln = tid & 63;
  __shared__ float u_s[CS];
  __shared__ float sm[4];

  // ---- P1: e = exp(S/eps), store fp8 E (pad=0), chunk column partials -> P
  {
    const int b0 = c * CS;
    const float4* S4 = (const float4*)(S + ((size_t)v * BATCH + b0) * KPROTO);
    unsigned* E4 = (unsigned*)(E + ((size_t)v * BATCH + b0) * KB);
    float* Pp = P + (size_t)(v * NCHUNK + c) * KB;
#pragma unroll
    for (int sub = 0; sub < 3; ++sub) {
      const int f = sub * NT + tid;  // 4-col group, 0..767
      float4 acc = make_float4(0.f, 0.f, 0.f, 0.f);
      if (f < KPROTO / 4) {
#pragma unroll 4
        for (int b = 0; b < CS; ++b) {
          float4 s = S4[(size_t)b * (KPROTO / 4) + f];
          float ex = __expf(s.x * EPS_INV), ey = __expf(s.y * EPS_INV);
          float ez = __expf(s.z * EPS_INV), ew = __expf(s.w * EPS_INV);
          acc.x += ex; acc.y += ey; acc.z += ez; acc.w += ew;
          int pk = __builtin_amdgcn_cvt_pk_fp8_f32(ex, ey, 0, false);
          pk = __builtin_amdgcn_cvt_pk_fp8_f32(ez, ew, pk, true);
          E4[(size_t)b * (KB / 4) + f] = (unsigned)pk;
        }
      } else {
#pragma unroll 4
        for (int b = 0; b < CS; ++b) E4[(size_t)b * (KB / 4) + f] = 0u;
      }
      ((float4*)Pp)[f] = acc;
    }
  }
  grid_barrier(bar, 0, blk);
  reduce_phase(P, V, blk, tid);  // V1
  grid_barrier(bar, 1, blk);
  fused_phase(E, V, P, v, c, wv, ln, tid, u_s);  // iter1 col-norm + iter2 partials
  grid_barrier(bar, 2, blk);
  reduce_phase(P, V, blk, tid);  // V2
  grid_barrier(bar, 3, blk);
  fused_phase(E, V, P, v, c, wv, ln, tid, u_s);  // iter2 col-norm + iter3 partials
  grid_barrier(bar, 4, blk);
  reduce_phase(P, V, blk, tid);  // V3
  grid_barrier(bar, 5, blk);

  // ---- Loss: each wave handles 2 rows; block covers rows [blk*8, blk*8+8).
  {
    const float4* V0 = (const float4*)V;
    const float4* V1 = (const float4*)(V + KB);
    float lossAcc = 0.f;
#pragma unroll
    for (int r = 0; r < 2; ++r) {
      const int b = blk * 8 + wv * 2 + r;
      const uint4* r0 = (const uint4*)(E + (size_t)b * KB);
      const uint4* r1 = (const uint4*)(E + ((size_t)BATCH + b) * KB);
      float c0 = 0.f, c1 = 0.f, se0 = 0.f, se1 = 0.f;
      float cr00 = 0.f, cr01 = 0.f, cr10 = 0.f, cr11 = 0.f;
#pragma unroll
      for (int q = 0; q < 3; ++q) {
        const int f = q * 64 + ln;
        uint4 p0 = r0[f], p1 = r1[f];
#define GRP(pu0, pu1, idx)                                \
  {                                                       \
    float4 ea = dec4(pu0), eb = dec4(pu1);                \
    float4 va = V0[4 * f + idx], vb = V1[4 * f + idx];    \
    _Pragma("unroll") for (int t = 0; t < 4; ++t) {       \
      float e0r = (&ea.x)[t], e1r = (&eb.x)[t];           \
      float ev0 = e0r * (&va.x)[t];                       \
      float ev1 = e1r * (&vb.x)[t];                       \
      float st0 = 0.5f * __logf(fmaxf(e0r, 1e-30f));      \
      float st1 = 0.5f * __logf(fmaxf(e1r, 1e-30f));      \
      se0 += fast_sqrt(e0r);                              \
      se1 += fast_sqrt(e1r);                              \
      c0 += ev0; c1 += ev1;                               \
      cr00 += ev0 * st0; cr01 += ev0 * st1;               \
      cr10 += ev1 * st0; cr11 += ev1 * st1;               \
    }                                                     \
  }
        GRP(p0.x, p1.x, 0)
        GRP(p0.y, p1.y, 1)
        GRP(p0.z, p1.z, 2)
        GRP(p0.w, p1.w, 3)
#undef GRP
      }
      c0 = wave_sum(c0);   c1 = wave_sum(c1);
      se0 = wave_sum(se0); se1 = wave_sum(se1);
      cr00 = wave_sum(cr00); cr01 = wave_sum(cr01);
      cr10 = wave_sum(cr10); cr11 = wave_sum(cr11);
      if (ln == 0) {
        const float cArr[2] = {c0, c1};
        const float seArr[2] = {se0, se1};
        const float cr[2][2] = {{cr00, cr01}, {cr10, cr11}};
#pragma unroll
        for (int p = 0; p < 2; ++p) {
          const int s = ci[p] & 1;
          const int t = si[p] & 1;
          lossAcc += __logf(seArr[t]) * (1.0f / BF) - cr[s][t] * fast_rcp(cArr[s] * BF);
        }
      }
    }
    if (ln == 0) sm[wv] = lossAcc;
    __syncthreads();
    if (tid == 0) partials[blk] = sm[0] + sm[1] + sm[2] + sm[3];
  }
  grid_barrier(bar, 6, blk);

  // ---- Final: block 0 reduces 512 partials -> out[0]
  if (blk == 0) {
    float a = partials[tid] + partials[tid + NT];
    a = wave_sum(a);
    if (ln == 0) sm[wv] = a;
    __syncthreads();
    if (tid == 0) out[0] = sm[0] + sm[1] + sm[2] + sm[3];
  }
}

extern "C" void kernel_launch(void* const* d_in, const int* in_sizes, int n_in,
                              void* d_out, int out_size, void* d_ws, size_t ws_size,
                              hipStream_t stream) {
  const float* S = (const float*)d_in[0];
  const int* code_ids = (const int*)d_in[1];  // int32 on the wire
  const int* score_ids = (const int*)d_in[2];

  // ws layout: bar (8 KB, uints) | V [2][KB] fl | partials [512] fl | P | E fp8
  unsigned* bar = (unsigned*)d_ws;
  float* V = (float*)d_ws + 2048;
  float* partials = V + NVIEWS * KB;
  float* P = partials + NBLK;
  unsigned char* E = (unsigned char*)(P + (size_t)NVIEWS * NCHUNK * KB);

  hipMemsetAsync(bar, 0, BAR_UINTS * sizeof(unsigned), stream);

  float* outp = (float*)d_out;
  mega_kernel<<<NBLK, NT, 0, stream>>>(S, code_ids, score_ids, E, P, V,
                                       partials, bar, outp);
}

// Round 10
// 244.080 us; speedup vs baseline: 1.5952x; 1.5952x over previous
//
#include <hip/hip_runtime.h>

// SwappedPredictionLoss: Sinkhorn-Knopp (3 iters) + swapped cross-entropy.
//
// q[b,k] = B * e_bk * u_b * v_k,  e = exp(S/eps)
//   row-normalize: v_k = 1/(K*R_k),  R_k = sum_b e_bk * u_b
//   col-normalize: u_b = 1/(B*C_b),  C_b = sum_k e_bk * v_k
// loss = sum_pairs [ (1/B) sum_b lse_t[b] - sum_b u_b * sum_k e_s*v_k*(S_t/T) ]
// From e alone (eps/T = 0.5):  S/T = 0.5*ln(e),  exp(S/T) = sqrt(e).
//
// R4: cross-phase fusion latency-bound. R5: hot global atomics banned.
// R6: privatized partial planes. R7: fp8 e4m3 E = 228 us (best).
// R8: hipLaunchCooperativeKernel silently no-ops here. R9: manual-barrier
// mega-kernel = 297 us alone (441 GB/s): serial 12-block reduces, 8 waves/CU
// everywhere, L2-invalidating fences — mega branch abandoned.
// R10 = R7 skeleton with: (1) chunk-local fused rowsum+colsum kernel
// (phase-B E read hits L2), (2) wide reduce (12 blk x 1024 thr, 8-way
// y-split), (3) no atomics/memsets. 8 launches.
// Harness notes: int inputs arrive int32; ~57us ws re-poison fill is inside
// the timed window and irreducible.

#define NVIEWS 2
#define BATCH 4096
#define KPROTO 3000
#define KB 3072      // padded fp8 row stride (bytes); V row length (floats)
#define NT 256
#define PSTRIDE 512  // plane-index stride per view in P
#define CS1 32       // rows per chunk in p1 (128 chunks)
#define CSF 8        // rows per chunk in fused (512 chunks)
#define LOSS_BLOCKS 1024

constexpr float EPS_INV = 20.0f;  // 1/0.05
constexpr float KF = 3000.0f;
constexpr float BF = 4096.0f;

typedef float floatx2 __attribute__((ext_vector_type(2)));

__device__ __forceinline__ float fast_rcp(float x) { return __builtin_amdgcn_rcpf(x); }
__device__ __forceinline__ float fast_sqrt(float x) { return __builtin_amdgcn_sqrtf(x); }

__device__ __forceinline__ float wave_sum(float x) {
#pragma unroll
  for (int o = 32; o > 0; o >>= 1) x += __shfl_down(x, o, 64);
  return x;
}

__device__ __forceinline__ float4 dec4(unsigned u) {
  floatx2 lo = __builtin_amdgcn_cvt_pk_f32_fp8((int)u, false);
  floatx2 hi = __builtin_amdgcn_cvt_pk_f32_fp8((int)u, true);
  return make_float4(lo.x, lo.y, hi.x, hi.y);
}

// P1: e = exp(S/eps); store fp8 E (pad=0); per-chunk column partials -> P.
// grid 768: c = i&127 (32-row chunk), m = i>>7: v = m/3, sub = m%3.
__global__ __launch_bounds__(NT) void p1_kernel(const float* __restrict__ S,
                                                unsigned char* __restrict__ E,
                                                float* __restrict__ P) {
  const int i = blockIdx.x;
  const int c = i & 127;
  const int m = i >> 7;
  const int v = m / 3;
  const int sub = m - v * 3;
  const int f = sub * NT + threadIdx.x;  // 4-col group, 0..767
  const int b0 = c * CS1;
  float4 acc = make_float4(0.f, 0.f, 0.f, 0.f);
  unsigned* Erow = (unsigned*)(E + ((size_t)v * BATCH + b0) * KB) + f;
  if (f < KPROTO / 4) {
    const float4* S4 = (const float4*)(S + ((size_t)v * BATCH + b0) * KPROTO) + f;
#pragma unroll 4
    for (int b = 0; b < CS1; ++b) {
      float4 s = S4[(size_t)b * (KPROTO / 4)];
      float ex = __expf(s.x * EPS_INV), ey = __expf(s.y * EPS_INV);
      float ez = __expf(s.z * EPS_INV), ew = __expf(s.w * EPS_INV);
      acc.x += ex; acc.y += ey; acc.z += ez; acc.w += ew;
      int pk = __builtin_amdgcn_cvt_pk_fp8_f32(ex, ey, 0, false);
      pk = __builtin_amdgcn_cvt_pk_fp8_f32(ez, ew, pk, true);
      Erow[(size_t)b * (KB / 4)] = (unsigned)pk;
    }
  } else {
#pragma unroll 4
    for (int b = 0; b < CS1; ++b) Erow[(size_t)b * (KB / 4)] = 0u;  // e=0 pad
  }
  ((float4*)(P + (size_t)(v * PSTRIDE + c) * KB))[f] = acc;
}

// Wide reduce: V[v][k] = 1/max(K * sum_y P[v][y][k], tiny).
// grid 12 (v*6+sub), block 1024: col c = tid&127 (float4), ygroup g = tid>>7
// (8 groups); LDS folds the 8 partials.
__global__ __launch_bounds__(1024) void reduce_kernel(const float* __restrict__ P,
                                                      float* __restrict__ V,
                                                      int nplanes) {
  __shared__ float4 part[8][128];
  const int v = blockIdx.x / 6;
  const int sub = blockIdx.x - v * 6;
  const int c = threadIdx.x & 127;
  const int g = threadIdx.x >> 7;
  const int np8 = nplanes >> 3;
  const float4* base = (const float4*)(P + (size_t)v * PSTRIDE * KB) + sub * 128 + c;
  float4 a = make_float4(0.f, 0.f, 0.f, 0.f);
#pragma unroll 8
  for (int y = g * np8; y < (g + 1) * np8; ++y) {
    float4 p = base[(size_t)y * (KB / 4)];
    a.x += p.x; a.y += p.y; a.z += p.z; a.w += p.w;
  }
  part[g][c] = a;
  __syncthreads();
  if (threadIdx.x < 128) {
    float4 s = part[0][threadIdx.x];
#pragma unroll
    for (int g2 = 1; g2 < 8; ++g2) {
      float4 p = part[g2][threadIdx.x];
      s.x += p.x; s.y += p.y; s.z += p.z; s.w += p.w;
    }
    float4 o;
    o.x = fast_rcp(fmaxf(s.x * KF, 1e-35f));
    o.y = fast_rcp(fmaxf(s.y * KF, 1e-35f));
    o.z = fast_rcp(fmaxf(s.z * KF, 1e-35f));
    o.w = fast_rcp(fmaxf(s.w * KF, 1e-35f));
    ((float4*)(V + v * KB))[sub * 128 + threadIdx.x] = o;
  }
}

// Fused chunk-local rowsum + colsum for one 8-row chunk:
// phase A: 4 waves x 2 rows: u_b = 1/(B * sum_k e*V_k) -> LDS;
// phase B: colsum with u (E re-read hits L2) -> P plane. No atomics.
// grid 1024: v = blk>>9, c = blk&511.
__global__ __launch_bounds__(NT) void fused_kernel(const unsigned char* __restrict__ E,
                                                   const float* __restrict__ V,
                                                   float* __restrict__ P) {
  __shared__ float u_s[CSF];
  const int blk = blockIdx.x;
  const int v = blk >> 9;
  const int c = blk & 511;
  const int wv = threadIdx.x >> 6, ln = threadIdx.x & 63;
  const int b0 = c * CSF;
  const float4* V4 = (const float4*)(V + v * KB);
#pragma unroll
  for (int r = 0; r < 2; ++r) {
    const int bl = wv * 2 + r;  // 0..7
    const uint4* Erow = (const uint4*)(E + ((size_t)v * BATCH + b0 + bl) * KB);
    float acc = 0.f;
#pragma unroll
    for (int q = 0; q < 3; ++q) {
      const int f = q * 64 + ln;  // 16-fp8 group
      uint4 pk = Erow[f];
      float4 e0 = dec4(pk.x), e1 = dec4(pk.y), e2 = dec4(pk.z), e3 = dec4(pk.w);
      float4 v0 = V4[4 * f], v1 = V4[4 * f + 1], v2 = V4[4 * f + 2], v3 = V4[4 * f + 3];
      acc += e0.x * v0.x + e0.y * v0.y + e0.z * v0.z + e0.w * v0.w
           + e1.x * v1.x + e1.y * v1.y + e1.z * v1.z + e1.w * v1.w
           + e2.x * v2.x + e2.y * v2.y + e2.z * v2.z + e2.w * v2.w
           + e3.x * v3.x + e3.y * v3.y + e3.z * v3.z + e3.w * v3.w;
    }
    acc = wave_sum(acc);
    if (ln == 0) u_s[bl] = fast_rcp(acc * BF);
  }
  __syncthreads();
  const unsigned* Ecol = (const unsigned*)(E + ((size_t)v * BATCH + b0) * KB);
  float* Pp = P + (size_t)(v * PSTRIDE + c) * KB;
#pragma unroll
  for (int sub = 0; sub < 3; ++sub) {
    const int f = sub * NT + threadIdx.x;  // 4-col group, 0..767
    float4 acc = make_float4(0.f, 0.f, 0.f, 0.f);
#pragma unroll
    for (int b = 0; b < CSF; ++b) {
      float u = u_s[b];
      float4 e = dec4(Ecol[(size_t)b * (KB / 4) + f]);
      acc.x += e.x * u; acc.y += e.y * u; acc.z += e.z * u; acc.w += e.w * u;
    }
    ((float4*)Pp)[f] = acc;
  }
}

// Loss: one wave per row b; reads both views' E rows once. C3 inline.
// grid 1024: c = i&127, j = i>>7; b = c*32 + j*4 + wv.
__global__ __launch_bounds__(NT) void loss_kernel(const unsigned char* __restrict__ E,
                                                  const int* __restrict__ ci,
                                                  const int* __restrict__ si,
                                                  const float* __restrict__ V3,
                                                  float* __restrict__ part) {
  const int i = blockIdx.x;
  const int c = i & 127;
  const int j = i >> 7;
  const int wv = threadIdx.x >> 6, ln = threadIdx.x & 63;
  const int b = c * 32 + j * 4 + wv;
  const uint4* r0 = (const uint4*)(E + (size_t)b * KB);
  const uint4* r1 = (const uint4*)(E + ((size_t)BATCH + b) * KB);
  const float4* V0 = (const float4*)V3;
  const float4* V1 = (const float4*)(V3 + KB);
  float c0 = 0.f, c1 = 0.f, se0 = 0.f, se1 = 0.f;
  float cr00 = 0.f, cr01 = 0.f, cr10 = 0.f, cr11 = 0.f;
#pragma unroll
  for (int q = 0; q < 3; ++q) {
    const int f = q * 64 + ln;
    uint4 p0 = r0[f], p1 = r1[f];
#define GRP(pu0, pu1, idx)                                \
  {                                                       \
    float4 ea = dec4(pu0), eb = dec4(pu1);                \
    float4 va = V0[4 * f + idx], vb = V1[4 * f + idx];    \
    _Pragma("unroll") for (int t = 0; t < 4; ++t) {       \
      float e0r = (&ea.x)[t], e1r = (&eb.x)[t];           \
      float ev0 = e0r * (&va.x)[t];                       \
      float ev1 = e1r * (&vb.x)[t];                       \
      float st0 = 0.5f * __logf(fmaxf(e0r, 1e-30f));      \
      float st1 = 0.5f * __logf(fmaxf(e1r, 1e-30f));      \
      se0 += fast_sqrt(e0r);                              \
      se1 += fast_sqrt(e1r);                              \
      c0 += ev0; c1 += ev1;                               \
      cr00 += ev0 * st0; cr01 += ev0 * st1;               \
      cr10 += ev1 * st0; cr11 += ev1 * st1;               \
    }                                                     \
  }
    GRP(p0.x, p1.x, 0)
    GRP(p0.y, p1.y, 1)
    GRP(p0.z, p1.z, 2)
    GRP(p0.w, p1.w, 3)
#undef GRP
  }
  c0 = wave_sum(c0);   c1 = wave_sum(c1);
  se0 = wave_sum(se0); se1 = wave_sum(se1);
  cr00 = wave_sum(cr00); cr01 = wave_sum(cr01);
  cr10 = wave_sum(cr10); cr11 = wave_sum(cr11);
  __shared__ float sm[4];
  if (ln == 0) {
    const float cArr[2] = {c0, c1};
    const float seArr[2] = {se0, se1};
    const float cr[2][2] = {{cr00, cr01}, {cr10, cr11}};
    float loss = 0.f;
#pragma unroll
    for (int p = 0; p < 2; ++p) {
      const int s = ci[p] & 1;
      const int t = si[p] & 1;
      loss += __logf(seArr[t]) * (1.0f / BF) - cr[s][t] * fast_rcp(cArr[s] * BF);
    }
    sm[wv] = loss;
  }
  __syncthreads();
  if (threadIdx.x == 0) part[i] = sm[0] + sm[1] + sm[2] + sm[3];
}

__global__ void final_kernel(const float* __restrict__ part, float* __restrict__ out) {
  float a = 0.f;
  for (int i = threadIdx.x; i < LOSS_BLOCKS; i += NT) a += part[i];
  a = wave_sum(a);
  __shared__ float sm[4];
  const int ln = threadIdx.x & 63;
  const int w = threadIdx.x >> 6;
  if (ln == 0) sm[w] = a;
  __syncthreads();
  if (threadIdx.x == 0) out[0] = sm[0] + sm[1] + sm[2] + sm[3];
}

extern "C" void kernel_launch(void* const* d_in, const int* in_sizes, int n_in,
                              void* d_out, int out_size, void* d_ws, size_t ws_size,
                              hipStream_t stream) {
  const float* S = (const float*)d_in[0];
  const int* code_ids = (const int*)d_in[1];  // int32 on the wire
  const int* score_ids = (const int*)d_in[2];

  float* ws = (float*)d_ws;
  // ws (floats): V [2][KB] | part [1024] | P [2][512][KB] | E (fp8, 25 MB)
  float* V = ws;
  float* part = V + NVIEWS * KB;
  float* P = part + LOSS_BLOCKS;
  unsigned char* E = (unsigned char*)(P + (size_t)NVIEWS * PSTRIDE * KB);  // 16B-aligned

  dim3 b256(NT), b1024(1024);
  p1_kernel<<<768, b256, 0, stream>>>(S, E, P);
  reduce_kernel<<<12, b1024, 0, stream>>>(P, V, 128);
  fused_kernel<<<1024, b256, 0, stream>>>(E, V, P);
  reduce_kernel<<<12, b1024, 0, stream>>>(P, V, 512);
  fused_kernel<<<1024, b256, 0, stream>>>(E, V, P);
  reduce_kernel<<<12, b1024, 0, stream>>>(P, V, 512);
  loss_kernel<<<1024, b256, 0, stream>>>(E, code_ids, score_ids, V, part);
  final_kernel<<<1, b256, 0, stream>>>(part, (float*)d_out);
}

// Round 11
// 233.734 us; speedup vs baseline: 1.6659x; 1.0443x over previous
//
#include <hip/hip_runtime.h>

// SwappedPredictionLoss: Sinkhorn-Knopp (3 iters) + swapped cross-entropy.
//
// q[b,k] = B * e_bk * u_b * v_k,  e = exp(S/eps)
//   row-normalize: v_k = 1/(K*R_k),  R_k = sum_b e_bk * u_b
//   col-normalize: u_b = 1/(B*C_b),  C_b = sum_k e_bk * v_k
// loss = sum_pairs [ (1/B) sum_b lse_t[b] - sum_b u_b * sum_k e_s*v_k*(S_t/T) ]
// From e alone (eps/T = 0.5):  S/T = 0.5*ln(e),  exp(S/T) = sqrt(e).
//
// R4/R9/R10: cross-phase fusion & barriers lose — streaming-only kernels.
// R5: hot global atomics banned. R6: privatized partial planes + reduce.
// R7 (best, 228us): fp8 e4m3 E. R10: wide reduce good, fused kernel bad.
// R11: widen per-thread load streams (latency x bytes-in-flight bound):
//   colsum: 16 cols x 16 rows per thread (16 independent 16B loads),
//   rowsum/loss: 2 rows per wave (6/12 independent 16B loads),
//   keep wide reduce (12x1024), p1 unchanged.
// Harness notes: int inputs arrive int32; ~57us ws re-poison fill is inside
// the timed window, irreducible.

#define NVIEWS 2
#define BATCH 4096
#define KPROTO 3000
#define KB 3072       // padded fp8 row stride (bytes); V row length (floats)
#define NT 256
#define PSTRIDE 256   // plane slots per view in P
#define CS1 32        // rows per chunk in p1 (128 planes)
#define CSC 16        // rows per chunk in colsum (256 planes)
#define LOSS_BLOCKS 512

constexpr float EPS_INV = 20.0f;  // 1/0.05
constexpr float KF = 3000.0f;
constexpr float BF = 4096.0f;

typedef float floatx2 __attribute__((ext_vector_type(2)));

__device__ __forceinline__ float fast_rcp(float x) { return __builtin_amdgcn_rcpf(x); }
__device__ __forceinline__ float fast_sqrt(float x) { return __builtin_amdgcn_sqrtf(x); }

__device__ __forceinline__ float wave_sum(float x) {
#pragma unroll
  for (int o = 32; o > 0; o >>= 1) x += __shfl_down(x, o, 64);
  return x;
}

__device__ __forceinline__ float4 dec4(unsigned u) {
  floatx2 lo = __builtin_amdgcn_cvt_pk_f32_fp8((int)u, false);
  floatx2 hi = __builtin_amdgcn_cvt_pk_f32_fp8((int)u, true);
  return make_float4(lo.x, lo.y, hi.x, hi.y);
}

// P1: e = exp(S/eps); store fp8 E (pad=0); per-chunk column partials -> P.
// grid 768: c = i&127 (32-row chunk), m = i>>7: v = m/3, sub = m%3.
__global__ __launch_bounds__(NT) void p1_kernel(const float* __restrict__ S,
                                                unsigned char* __restrict__ E,
                                                float* __restrict__ P) {
  const int i = blockIdx.x;
  const int c = i & 127;
  const int m = i >> 7;
  const int v = m / 3;
  const int sub = m - v * 3;
  const int f = sub * NT + threadIdx.x;  // 4-col group, 0..767
  const int b0 = c * CS1;
  float4 acc = make_float4(0.f, 0.f, 0.f, 0.f);
  unsigned* Erow = (unsigned*)(E + ((size_t)v * BATCH + b0) * KB) + f;
  if (f < KPROTO / 4) {
    const float4* S4 = (const float4*)(S + ((size_t)v * BATCH + b0) * KPROTO) + f;
#pragma unroll 4
    for (int b = 0; b < CS1; ++b) {
      float4 s = S4[(size_t)b * (KPROTO / 4)];
      float ex = __expf(s.x * EPS_INV), ey = __expf(s.y * EPS_INV);
      float ez = __expf(s.z * EPS_INV), ew = __expf(s.w * EPS_INV);
      acc.x += ex; acc.y += ey; acc.z += ez; acc.w += ew;
      int pk = __builtin_amdgcn_cvt_pk_fp8_f32(ex, ey, 0, false);
      pk = __builtin_amdgcn_cvt_pk_fp8_f32(ez, ew, pk, true);
      Erow[(size_t)b * (KB / 4)] = (unsigned)pk;
    }
  } else {
#pragma unroll 4
    for (int b = 0; b < CS1; ++b) Erow[(size_t)b * (KB / 4)] = 0u;  // e=0 pad
  }
  ((float4*)(P + (size_t)(v * PSTRIDE + c) * KB))[f] = acc;
}

// Wide reduce: V[v][k] = 1/max(K * sum_y P[v][y][k], tiny).
// grid 12 (v*6+sub), block 1024: col = tid&127 (float4), ygroup = tid>>7.
__global__ __launch_bounds__(1024) void reduce_kernel(const float* __restrict__ P,
                                                      float* __restrict__ V,
                                                      int nplanes) {
  __shared__ float4 part[8][128];
  const int v = blockIdx.x / 6;
  const int sub = blockIdx.x - v * 6;
  const int c = threadIdx.x & 127;
  const int g = threadIdx.x >> 7;
  const int np8 = nplanes >> 3;
  const float4* base = (const float4*)(P + (size_t)v * PSTRIDE * KB) + sub * 128 + c;
  float4 a = make_float4(0.f, 0.f, 0.f, 0.f);
#pragma unroll 8
  for (int y = g * np8; y < (g + 1) * np8; ++y) {
    float4 p = base[(size_t)y * (KB / 4)];
    a.x += p.x; a.y += p.y; a.z += p.z; a.w += p.w;
  }
  part[g][c] = a;
  __syncthreads();
  if (threadIdx.x < 128) {
    float4 s = part[0][threadIdx.x];
#pragma unroll
    for (int g2 = 1; g2 < 8; ++g2) {
      float4 p = part[g2][threadIdx.x];
      s.x += p.x; s.y += p.y; s.z += p.z; s.w += p.w;
    }
    float4 o;
    o.x = fast_rcp(fmaxf(s.x * KF, 1e-35f));
    o.y = fast_rcp(fmaxf(s.y * KF, 1e-35f));
    o.z = fast_rcp(fmaxf(s.z * KF, 1e-35f));
    o.w = fast_rcp(fmaxf(s.w * KF, 1e-35f));
    ((float4*)(V + v * KB))[sub * 128 + threadIdx.x] = o;
  }
}

// Rowsum: U[v][b] = 1/(B * sum_k e*V_k). 2 rows per wave (6 indep 16B loads),
// V reads shared between the two rows. grid 1024: v = i>>9, rows (i&511)*8.
__global__ __launch_bounds__(NT) void rowsum_kernel(const unsigned char* __restrict__ E,
                                                    const float* __restrict__ V,
                                                    float* __restrict__ U) {
  const int i = blockIdx.x;
  const int v = i >> 9;
  const int base = (i & 511) * 8;
  const int wv = threadIdx.x >> 6, ln = threadIdx.x & 63;
  const int b = base + wv * 2;
  const uint4* r0 = (const uint4*)(E + ((size_t)v * BATCH + b) * KB);
  const uint4* r1 = (const uint4*)(E + ((size_t)v * BATCH + b + 1) * KB);
  const float4* V4 = (const float4*)(V + v * KB);
  float a0 = 0.f, a1 = 0.f;
#pragma unroll
  for (int q = 0; q < 3; ++q) {
    const int f = q * 64 + ln;  // 16-fp8 group
    uint4 p0 = r0[f], p1 = r1[f];
    float4 v0 = V4[4 * f], v1 = V4[4 * f + 1], v2 = V4[4 * f + 2], v3 = V4[4 * f + 3];
#define DOT(pk, acc)                                                   \
  {                                                                    \
    float4 e0 = dec4(pk.x), e1 = dec4(pk.y), e2 = dec4(pk.z), e3 = dec4(pk.w); \
    acc += e0.x * v0.x + e0.y * v0.y + e0.z * v0.z + e0.w * v0.w       \
         + e1.x * v1.x + e1.y * v1.y + e1.z * v1.z + e1.w * v1.w       \
         + e2.x * v2.x + e2.y * v2.y + e2.z * v2.z + e2.w * v2.w       \
         + e3.x * v3.x + e3.y * v3.y + e3.z * v3.z + e3.w * v3.w;      \
  }
    DOT(p0, a0)
    DOT(p1, a1)
#undef DOT
  }
  a0 = wave_sum(a0);
  a1 = wave_sum(a1);
  if (ln == 0) {
    U[v * BATCH + b] = fast_rcp(a0 * BF);
    U[v * BATCH + b + 1] = fast_rcp(a1 * BF);
  }
}

// Colsum: P[v][c][k] = sum over 16 chunk rows of e * u_b. Thread owns 16
// columns (uint4 per row) -> 16 independent 16B loads, 16 VGPR accumulators.
// grid 512 x 192 threads: v = i>>8, c = i&255.
__global__ __launch_bounds__(192) void colsum_kernel(const unsigned char* __restrict__ E,
                                                     const float* __restrict__ U,
                                                     float* __restrict__ P) {
  const int i = blockIdx.x;
  const int v = i >> 8;
  const int c = i & 255;
  const int t = threadIdx.x;  // 0..191, 16-col group
  const int b0 = c * CSC;
  const uint4* E16 = (const uint4*)(E + ((size_t)v * BATCH + b0) * KB) + t;
  const float* Uv = U + v * BATCH + b0;
  float4 ac0 = make_float4(0.f, 0.f, 0.f, 0.f);
  float4 ac1 = ac0, ac2 = ac0, ac3 = ac0;
#pragma unroll
  for (int b = 0; b < CSC; ++b) {
    float u = Uv[b];
    uint4 pk = E16[(size_t)b * (KB / 16)];
    float4 e0 = dec4(pk.x), e1 = dec4(pk.y), e2 = dec4(pk.z), e3 = dec4(pk.w);
    ac0.x += e0.x * u; ac0.y += e0.y * u; ac0.z += e0.z * u; ac0.w += e0.w * u;
    ac1.x += e1.x * u; ac1.y += e1.y * u; ac1.z += e1.z * u; ac1.w += e1.w * u;
    ac2.x += e2.x * u; ac2.y += e2.y * u; ac2.z += e2.z * u; ac2.w += e2.w * u;
    ac3.x += e3.x * u; ac3.y += e3.y * u; ac3.z += e3.z * u; ac3.w += e3.w * u;
  }
  float4* Pp = (float4*)(P + (size_t)(v * PSTRIDE + c) * KB) + t * 4;
  Pp[0] = ac0; Pp[1] = ac1; Pp[2] = ac2; Pp[3] = ac3;
}

// Loss: 2 rows per wave; block covers rows [blk*8, blk*8+8). C3 inline.
__global__ __launch_bounds__(NT) void loss_kernel(const unsigned char* __restrict__ E,
                                                  const int* __restrict__ ci,
                                                  const int* __restrict__ si,
                                                  const float* __restrict__ V3,
                                                  float* __restrict__ part) {
  const int blk = blockIdx.x;
  const int wv = threadIdx.x >> 6, ln = threadIdx.x & 63;
  const float4* V0 = (const float4*)V3;
  const float4* V1 = (const float4*)(V3 + KB);
  float lossAcc = 0.f;
#pragma unroll
  for (int r = 0; r < 2; ++r) {
    const int b = blk * 8 + wv * 2 + r;
    const uint4* r0 = (const uint4*)(E + (size_t)b * KB);
    const uint4* r1 = (const uint4*)(E + ((size_t)BATCH + b) * KB);
    float c0 = 0.f, c1 = 0.f, se0 = 0.f, se1 = 0.f;
    float cr00 = 0.f, cr01 = 0.f, cr10 = 0.f, cr11 = 0.f;
#pragma unroll
    for (int q = 0; q < 3; ++q) {
      const int f = q * 64 + ln;
      uint4 p0 = r0[f], p1 = r1[f];
#define GRP(pu0, pu1, idx)                                \
  {                                                       \
    float4 ea = dec4(pu0), eb = dec4(pu1);                \
    float4 va = V0[4 * f + idx], vb = V1[4 * f + idx];    \
    _Pragma("unroll") for (int t = 0; t < 4; ++t) {       \
      float e0r = (&ea.x)[t], e1r = (&eb.x)[t];           \
      float ev0 = e0r * (&va.x)[t];                       \
      float ev1 = e1r * (&vb.x)[t];                       \
      float st0 = 0.5f * __logf(fmaxf(e0r, 1e-30f));      \
      float st1 = 0.5f * __logf(fmaxf(e1r, 1e-30f));      \
      se0 += fast_sqrt(e0r);                              \
      se1 += fast_sqrt(e1r);                              \
      c0 += ev0; c1 += ev1;                               \
      cr00 += ev0 * st0; cr01 += ev0 * st1;               \
      cr10 += ev1 * st0; cr11 += ev1 * st1;               \
    }                                                     \
  }
      GRP(p0.x, p1.x, 0)
      GRP(p0.y, p1.y, 1)
      GRP(p0.z, p1.z, 2)
      GRP(p0.w, p1.w, 3)
#undef GRP
    }
    c0 = wave_sum(c0);   c1 = wave_sum(c1);
    se0 = wave_sum(se0); se1 = wave_sum(se1);
    cr00 = wave_sum(cr00); cr01 = wave_sum(cr01);
    cr10 = wave_sum(cr10); cr11 = wave_sum(cr11);
    if (ln == 0) {
      const float cArr[2] = {c0, c1};
      const float seArr[2] = {se0, se1};
      const float cr[2][2] = {{cr00, cr01}, {cr10, cr11}};
#pragma unroll
      for (int p = 0; p < 2; ++p) {
        const int s = ci[p] & 1;
        const int t = si[p] & 1;
        lossAcc += __logf(seArr[t]) * (1.0f / BF) - cr[s][t] * fast_rcp(cArr[s] * BF);
      }
    }
  }
  __shared__ float sm[4];
  if (ln == 0) sm[wv] = lossAcc;
  __syncthreads();
  if (threadIdx.x == 0) part[blk] = sm[0] + sm[1] + sm[2] + sm[3];
}

__global__ void final_kernel(const float* __restrict__ part, float* __restrict__ out) {
  float a = 0.f;
  for (int i = threadIdx.x; i < LOSS_BLOCKS; i += NT) a += part[i];
  a = wave_sum(a);
  __shared__ float sm[4];
  const int ln = threadIdx.x & 63;
  const int w = threadIdx.x >> 6;
  if (ln == 0) sm[w] = a;
  __syncthreads();
  if (threadIdx.x == 0) out[0] = sm[0] + sm[1] + sm[2] + sm[3];
}

extern "C" void kernel_launch(void* const* d_in, const int* in_sizes, int n_in,
                              void* d_out, int out_size, void* d_ws, size_t ws_size,
                              hipStream_t stream) {
  const float* S = (const float*)d_in[0];
  const int* code_ids = (const int*)d_in[1];  // int32 on the wire
  const int* score_ids = (const int*)d_in[2];

  float* ws = (float*)d_ws;
  // ws (floats): V [2][KB] | U [2][BATCH] | part [512] | P [2][256][KB] | E fp8
  float* V = ws;
  float* U = V + NVIEWS * KB;
  float* part = U + NVIEWS * BATCH;
  float* P = part + LOSS_BLOCKS;
  unsigned char* E = (unsigned char*)(P + (size_t)NVIEWS * PSTRIDE * KB);  // 16B-aligned

  dim3 b256(NT), b192(192), b1024(1024);
  p1_kernel<<<768, b256, 0, stream>>>(S, E, P);
  reduce_kernel<<<12, b1024, 0, stream>>>(P, V, 128);
  rowsum_kernel<<<1024, b256, 0, stream>>>(E, V, U);
  colsum_kernel<<<512, b192, 0, stream>>>(E, U, P);
  reduce_kernel<<<12, b1024, 0, stream>>>(P, V, 256);
  rowsum_kernel<<<1024, b256, 0, stream>>>(E, V, U);
  colsum_kernel<<<512, b192, 0, stream>>>(E, U, P);
  reduce_kernel<<<12, b1024, 0, stream>>>(P, V, 256);
  loss_kernel<<<LOSS_BLOCKS, b256, 0, stream>>>(E, code_ids, score_ids, V, part);
  final_kernel<<<1, b256, 0, stream>>>(part, (float*)d_out);
}

// Round 12
// 223.933 us; speedup vs baseline: 1.7388x; 1.0438x over previous
//
#include <hip/hip_runtime.h>

// SwappedPredictionLoss: Sinkhorn-Knopp (3 iters) + swapped cross-entropy.
//
// q[b,k] = B * e_bk * u_b * v_k,  e = exp(S/eps)
//   row-normalize: v_k = 1/(K*R_k),  R_k = sum_b e_bk * u_b
//   col-normalize: u_b = 1/(B*C_b),  C_b = sum_k e_bk * v_k
// loss = sum_pairs [ (1/B) sum_b lse_t[b] - sum_b u_b * sum_k e_s*v_k*(S_t/T) ]
// From e alone (eps/T = 0.5):  S/T = 0.5*ln(e),  exp(S/T) = sqrt(e).
//
// R4/R9/R10: cross-phase fusion & barriers lose — streaming-only kernels.
// R5: hot global atomics banned. R6: privatized partial planes + reduce.
// R7 = best structure (228 us). R11: per-thread stream widening FALSIFIED
// (R7's narrow shapes faster). NEW: reduce kernels are CU-COUNT-bound
// (~25 GB/s per CU): 6 blocks = 6 CUs = 15-20 us each. R12 = R7 verbatim +
// 96-block reduce (96 CUs, 16 cols x 16 ygroups per block, LDS fold) ~2-3 us.
// Harness notes: int inputs arrive int32; ~58us ws re-poison fill is inside
// the timed window, irreducible.

#define NVIEWS 2
#define BATCH 4096
#define KPROTO 3000
#define KB 3072      // padded fp8 row stride (bytes); V row length (floats)
#define NT 256
#define CS 32        // rows per chunk
#define NCHUNK 128   // BATCH / CS planes per view
#define LOSS_BLOCKS 1024

constexpr float EPS_INV = 20.0f;  // 1/0.05
constexpr float KF = 3000.0f;
constexpr float BF = 4096.0f;

typedef float floatx2 __attribute__((ext_vector_type(2)));

__device__ __forceinline__ float fast_rcp(float x) { return __builtin_amdgcn_rcpf(x); }
__device__ __forceinline__ float fast_sqrt(float x) { return __builtin_amdgcn_sqrtf(x); }

__device__ __forceinline__ float wave_sum(float x) {
#pragma unroll
  for (int o = 32; o > 0; o >>= 1) x += __shfl_down(x, o, 64);
  return x;
}

__device__ __forceinline__ float4 dec4(unsigned u) {
  floatx2 lo = __builtin_amdgcn_cvt_pk_f32_fp8((int)u, false);
  floatx2 hi = __builtin_amdgcn_cvt_pk_f32_fp8((int)u, true);
  return make_float4(lo.x, lo.y, hi.x, hi.y);
}

// P1: e = exp(S/eps); store fp8 E (pad=0); per-chunk column partials -> P.
// grid 768: c = i&127 (32-row chunk), m = i>>7: v = m/3, sub = m%3.
__global__ __launch_bounds__(NT) void p1_kernel(const float* __restrict__ S,
                                                unsigned char* __restrict__ E,
                                                float* __restrict__ P) {
  const int i = blockIdx.x;
  const int c = i & 127;
  const int m = i >> 7;
  const int v = m / 3;
  const int sub = m - v * 3;
  const int f = sub * NT + threadIdx.x;  // 4-col group, 0..767
  const int b0 = c * CS;
  float4 acc = make_float4(0.f, 0.f, 0.f, 0.f);
  unsigned* Erow = (unsigned*)(E + ((size_t)v * BATCH + b0) * KB) + f;
  if (f < KPROTO / 4) {
    const float4* S4 = (const float4*)(S + ((size_t)v * BATCH + b0) * KPROTO) + f;
#pragma unroll 4
    for (int b = 0; b < CS; ++b) {
      float4 s = S4[(size_t)b * (KPROTO / 4)];
      float ex = __expf(s.x * EPS_INV), ey = __expf(s.y * EPS_INV);
      float ez = __expf(s.z * EPS_INV), ew = __expf(s.w * EPS_INV);
      acc.x += ex; acc.y += ey; acc.z += ez; acc.w += ew;
      int pk = __builtin_amdgcn_cvt_pk_fp8_f32(ex, ey, 0, false);
      pk = __builtin_amdgcn_cvt_pk_fp8_f32(ez, ew, pk, true);
      Erow[(size_t)b * (KB / 4)] = (unsigned)pk;
    }
  } else {
#pragma unroll 4
    for (int b = 0; b < CS; ++b) Erow[(size_t)b * (KB / 4)] = 0u;  // e=0 pad
  }
  ((float4*)(P + (size_t)(v * NCHUNK + c) * KB))[f] = acc;
}

// Reduce: V[v][k] = 1/max(K * sum_y P[v][y][k], tiny).
// grid 96 (v*48+sub), block 256 = 16 ygroups x 16 cols; LDS folds ygroups.
// 96 CUs active (CU-count-bound fix: per-CU stream BW ~25 GB/s).
__global__ __launch_bounds__(NT) void reduce_kernel(const float* __restrict__ P,
                                                    float* __restrict__ V) {
  __shared__ float4 sm[16][17];
  const int v = blockIdx.x / 48;
  const int sub = blockIdx.x - v * 48;
  const int cl = threadIdx.x & 15;
  const int yg = threadIdx.x >> 4;
  const int col4 = sub * 16 + cl;  // float4-column, 0..767
  const float4* base = (const float4*)(P + (size_t)v * NCHUNK * KB) + col4;
  float4 a = make_float4(0.f, 0.f, 0.f, 0.f);
#pragma unroll
  for (int y = yg * 8; y < yg * 8 + 8; ++y) {
    float4 p = base[(size_t)y * (KB / 4)];
    a.x += p.x; a.y += p.y; a.z += p.z; a.w += p.w;
  }
  sm[yg][cl] = a;
  __syncthreads();
  if (yg == 0) {
    float4 s = sm[0][cl];
#pragma unroll
    for (int g = 1; g < 16; ++g) {
      float4 p = sm[g][cl];
      s.x += p.x; s.y += p.y; s.z += p.z; s.w += p.w;
    }
    float4 o;
    o.x = fast_rcp(fmaxf(s.x * KF, 1e-35f));
    o.y = fast_rcp(fmaxf(s.y * KF, 1e-35f));
    o.z = fast_rcp(fmaxf(s.z * KF, 1e-35f));
    o.w = fast_rcp(fmaxf(s.w * KF, 1e-35f));
    ((float4*)(V + v * KB))[col4] = o;
  }
}

// Rowsum: U[v][b] = 1/(B * sum_k e*V_k). One wave per row (R7 shape).
// grid 2048: c = i&127, m = i>>7: j = m&7, v = m>>3; b = c*32 + j*4 + wv.
__global__ __launch_bounds__(NT) void rowsum_kernel(const unsigned char* __restrict__ E,
                                                    const float* __restrict__ V,
                                                    float* __restrict__ U) {
  const int i = blockIdx.x;
  const int c = i & 127;
  const int m = i >> 7;
  const int j = m & 7;
  const int v = m >> 3;
  const int wv = threadIdx.x >> 6, ln = threadIdx.x & 63;
  const int b = c * CS + j * 4 + wv;
  const uint4* Erow = (const uint4*)(E + ((size_t)v * BATCH + b) * KB);
  const float4* V4 = (const float4*)(V + v * KB);
  float acc = 0.f;
#pragma unroll
  for (int q = 0; q < 3; ++q) {
    const int f = q * 64 + ln;  // 16-fp8 group, 0..191
    uint4 pk = Erow[f];
    float4 e0 = dec4(pk.x), e1 = dec4(pk.y), e2 = dec4(pk.z), e3 = dec4(pk.w);
    float4 v0 = V4[4 * f], v1 = V4[4 * f + 1], v2 = V4[4 * f + 2], v3 = V4[4 * f + 3];
    acc += e0.x * v0.x + e0.y * v0.y + e0.z * v0.z + e0.w * v0.w
         + e1.x * v1.x + e1.y * v1.y + e1.z * v1.z + e1.w * v1.w
         + e2.x * v2.x + e2.y * v2.y + e2.z * v2.z + e2.w * v2.w
         + e3.x * v3.x + e3.y * v3.y + e3.z * v3.z + e3.w * v3.w;
  }
  acc = wave_sum(acc);
  if (ln == 0) U[v * BATCH + b] = fast_rcp(acc * BF);
}

// Colsum: P[v][c][k] = sum over 32 chunk rows of e * u_b (R7 shape, no atomics).
__global__ __launch_bounds__(NT) void colsum_kernel(const unsigned char* __restrict__ E,
                                                    const float* __restrict__ U,
                                                    float* __restrict__ P) {
  const int i = blockIdx.x;
  const int c = i & 127;
  const int m = i >> 7;
  const int v = m / 3;
  const int sub = m - v * 3;
  const int f = sub * NT + threadIdx.x;  // 4-col group
  const int b0 = c * CS;
  const unsigned* Ecol = (const unsigned*)(E + ((size_t)v * BATCH + b0) * KB) + f;
  const float* Uv = U + v * BATCH + b0;
  float4 acc = make_float4(0.f, 0.f, 0.f, 0.f);
#pragma unroll 8
  for (int b = 0; b < CS; ++b) {
    float u = Uv[b];
    float4 e = dec4(Ecol[(size_t)b * (KB / 4)]);
    acc.x += e.x * u; acc.y += e.y * u; acc.z += e.z * u; acc.w += e.w * u;
  }
  ((float4*)(P + (size_t)(v * NCHUNK + c) * KB))[f] = acc;
}

// Loss: one wave per row b; reads both views' E rows once. C3 inline (R7 shape).
// grid 1024: c = i&127, j = i>>7; b = c*32 + j*4 + wv.
__global__ __launch_bounds__(NT) void loss_kernel(const unsigned char* __restrict__ E,
                                                  const int* __restrict__ ci,
                                                  const int* __restrict__ si,
                                                  const float* __restrict__ V3,
                                                  float* __restrict__ part) {
  const int i = blockIdx.x;
  const int c = i & 127;
  const int j = i >> 7;
  const int wv = threadIdx.x >> 6, ln = threadIdx.x & 63;
  const int b = c * CS + j * 4 + wv;
  const uint4* r0 = (const uint4*)(E + (size_t)b * KB);
  const uint4* r1 = (const uint4*)(E + ((size_t)BATCH + b) * KB);
  const float4* V0 = (const float4*)V3;
  const float4* V1 = (const float4*)(V3 + KB);
  float c0 = 0.f, c1 = 0.f, se0 = 0.f, se1 = 0.f;
  float cr00 = 0.f, cr01 = 0.f, cr10 = 0.f, cr11 = 0.f;
#pragma unroll
  for (int q = 0; q < 3; ++q) {
    const int f = q * 64 + ln;
    uint4 p0 = r0[f], p1 = r1[f];
#define GRP(pu0, pu1, idx)                                \
  {                                                       \
    float4 ea = dec4(pu0), eb = dec4(pu1);                \
    float4 va = V0[4 * f + idx], vb = V1[4 * f + idx];    \
    _Pragma("unroll") for (int t = 0; t < 4; ++t) {       \
      float e0r = (&ea.x)[t], e1r = (&eb.x)[t];           \
      float ev0 = e0r * (&va.x)[t];                       \
      float ev1 = e1r * (&vb.x)[t];                       \
      float st0 = 0.5f * __logf(fmaxf(e0r, 1e-30f));      \
      float st1 = 0.5f * __logf(fmaxf(e1r, 1e-30f));      \
      se0 += fast_sqrt(e0r);                              \
      se1 += fast_sqrt(e1r);                              \
      c0 += ev0; c1 += ev1;                               \
      cr00 += ev0 * st0; cr01 += ev0 * st1;               \
      cr10 += ev1 * st0; cr11 += ev1 * st1;               \
    }                                                     \
  }
    GRP(p0.x, p1.x, 0)
    GRP(p0.y, p1.y, 1)
    GRP(p0.z, p1.z, 2)
    GRP(p0.w, p1.w, 3)
#undef GRP
  }
  c0 = wave_sum(c0);   c1 = wave_sum(c1);
  se0 = wave_sum(se0); se1 = wave_sum(se1);
  cr00 = wave_sum(cr00); cr01 = wave_sum(cr01);
  cr10 = wave_sum(cr10); cr11 = wave_sum(cr11);
  __shared__ float sm[4];
  if (ln == 0) {
    const float cArr[2] = {c0, c1};
    const float seArr[2] = {se0, se1};
    const float cr[2][2] = {{cr00, cr01}, {cr10, cr11}};
    float loss = 0.f;
#pragma unroll
    for (int p = 0; p < 2; ++p) {
      const int s = ci[p] & 1;
      const int t = si[p] & 1;
      loss += __logf(seArr[t]) * (1.0f / BF) - cr[s][t] * fast_rcp(cArr[s] * BF);
    }
    sm[wv] = loss;
  }
  __syncthreads();
  if (threadIdx.x == 0) part[i] = sm[0] + sm[1] + sm[2] + sm[3];
}

__global__ void final_kernel(const float* __restrict__ part, float* __restrict__ out) {
  float a = 0.f;
  for (int i = threadIdx.x; i < LOSS_BLOCKS; i += NT) a += part[i];
  a = wave_sum(a);
  __shared__ float sm[4];
  const int ln = threadIdx.x & 63;
  const int w = threadIdx.x >> 6;
  if (ln == 0) sm[w] = a;
  __syncthreads();
  if (threadIdx.x == 0) out[0] = sm[0] + sm[1] + sm[2] + sm[3];
}

extern "C" void kernel_launch(void* const* d_in, const int* in_sizes, int n_in,
                              void* d_out, int out_size, void* d_ws, size_t ws_size,
                              hipStream_t stream) {
  const float* S = (const float*)d_in[0];
  const int* code_ids = (const int*)d_in[1];  // int32 on the wire
  const int* score_ids = (const int*)d_in[2];

  float* ws = (float*)d_ws;
  // ws (floats): V [2][KB] | U [2][BATCH] | part [1024] | P [2][128][KB] | E fp8
  float* V = ws;
  float* U = V + NVIEWS * KB;
  float* part = U + NVIEWS * BATCH;
  float* P = part + LOSS_BLOCKS;
  unsigned char* E = (unsigned char*)(P + (size_t)NVIEWS * NCHUNK * KB);  // 16B-aligned

  dim3 blk(NT);
  p1_kernel<<<768, blk, 0, stream>>>(S, E, P);
  reduce_kernel<<<96, blk, 0, stream>>>(P, V);
  rowsum_kernel<<<2048, blk, 0, stream>>>(E, V, U);
  colsum_kernel<<<768, blk, 0, stream>>>(E, U, P);
  reduce_kernel<<<96, blk, 0, stream>>>(P, V);
  rowsum_kernel<<<2048, blk, 0, stream>>>(E, V, U);
  colsum_kernel<<<768, blk, 0, stream>>>(E, U, P);
  reduce_kernel<<<96, blk, 0, stream>>>(P, V);
  loss_kernel<<<1024, blk, 0, stream>>>(E, code_ids, score_ids, V, part);
  final_kernel<<<1, blk, 0, stream>>>(part, (float*)d_out);
}